// Round 5
// baseline (749.846 us; speedup 1.0000x reference)
//
#include <hip/hip_runtime.h>
#include <math.h>

#define NN    2048
#define BATCH 32
#define TILE  64
#define TPB   256
#define TPS   (NN / TILE)          // 32 tiles per side
#define NPOS  (TPS * TPS)          // 1024 tile positions
#define BGRP  8                    // batch-groups per tile position
#define BPG   (BATCH / BGRP)       // 4 batches per block
#define GRID_MAIN (NPOS * BGRP)    // 8192 blocks

// Path-A workspace need: one float per (batch, tile-position) = 128 KiB.
#define WS_NEED ((size_t)BATCH * NPOS * sizeof(float))

// out[b] = sigmoid(coef[0] + coef[1] + coef[2]*S1[b] + coef[3]*S2[b])
//   S1[b] = sum_ij Ms[1,0,i,j] * x[b,j,i]
//   S2[b] = sum_ij Ms[1,1,i,j] * x[b,j,i]^2
// (r=0 rows of Ms are never needed: trace^0 == 1.)
//
// Each block: one 64x64 (i,j) tile position + 4 batches. Ms fragments live in
// registers (loaded once, coalesced). Per batch: stage the transposed x tile
// into LDS with float4 coalesced loads, read back transposed (65-float pitch:
// 2 lanes/bank = free), accumulate the coef-weighted scalar, reduce, emit one
// partial float (Path A: ws slot; Path B: atomicAdd into out[b]).
template <int USE_WS>
__global__ __launch_bounds__(TPB) void trace_kernel(
    const float* __restrict__ x,     // (B, N, N)
    const float* __restrict__ Ms,    // (2, 2, N, N)
    const float* __restrict__ coef,  // (2, 2) flat [c00,c01,c10,c11]
    float* __restrict__ ws,          // Path A: [b*NPOS + pos]
    float* __restrict__ out)         // Path B: pre-zeroed accumulators
{
    __shared__ float xs[TILE][TILE + 1];
    __shared__ float wsum[TPB / 64];

    const int t    = threadIdx.x;
    const int pos  = blockIdx.x >> 3;           // / BGRP
    const int grp  = blockIdx.x & (BGRP - 1);
    const int i0   = (pos / TPS) * TILE;
    const int j0   = (pos % TPS) * TILE;

    const int lane    = t & 63;
    const int wave    = t >> 6;
    const int jl      = t & 63;    // compute: lane spans j (contiguous for M)
    const int il_base = t >> 6;    // compute: i = il_base + 4k

    const float c2 = coef[2];
    const float c3 = coef[3];

    // Ms fragments -> registers (once per block; lanes contiguous in j).
    const float* __restrict__ M10 = Ms + (size_t)2 * NN * NN;
    const float* __restrict__ M11 = Ms + (size_t)3 * NN * NN;
    float m10[16], m11[16];
#pragma unroll
    for (int k = 0; k < 16; ++k) {
        const size_t off = (size_t)(i0 + il_base + 4 * k) * NN + (size_t)(j0 + jl);
        m10[k] = M10[off];
        m11[k] = M11[off];
    }

    // staging mapping: 16 lanes x float4 per row, 16 rows per pass, 4 passes.
    const int sj  = t >> 4;          // 0..15
    const int si4 = (t & 15) * 4;    // 0..60

    for (int bb = 0; bb < BPG; ++bb) {
        const int b = grp * BPG + bb;
        const float* __restrict__ xb = x + (size_t)b * NN * NN;

        // stage xs[row][col] = x[b, j0+row, i0+col]  (coalesced float4)
#pragma unroll
        for (int k = 0; k < 4; ++k) {
            const int row = sj + 16 * k;
            const float4 v = *reinterpret_cast<const float4*>(
                xb + (size_t)(j0 + row) * NN + (size_t)(i0 + si4));
            xs[row][si4 + 0] = v.x;
            xs[row][si4 + 1] = v.y;
            xs[row][si4 + 2] = v.z;
            xs[row][si4 + 3] = v.w;
        }
        __syncthreads();

        float z = 0.f;
        {
            float s1 = 0.f, s2 = 0.f;
#pragma unroll
            for (int k = 0; k < 16; ++k) {
                const float v = xs[jl][il_base + 4 * k];   // x[b, j, i]
                s1 = fmaf(m10[k], v, s1);
                s2 = fmaf(m11[k], v * v, s2);
            }
            z = fmaf(c2, s1, c3 * s2);   // fold coef weights before reduction
        }

#pragma unroll
        for (int o = 32; o > 0; o >>= 1) z += __shfl_xor(z, o, 64);
        if (lane == 0) wsum[wave] = z;
        __syncthreads();

        if (t == 0) {
            const float zt = wsum[0] + wsum[1] + wsum[2] + wsum[3];
            if (USE_WS) {
                ws[(size_t)b * NPOS + pos] = zt;
            } else {
                atomicAdd(&out[b], zt);
            }
        }
        // no trailing barrier needed: next stage's xs writes are ordered after
        // this iteration's xs reads by the sync above; wsum WAR is ordered by
        // the next iteration's post-stage sync (t0's read precedes its arrival).
    }
}

__global__ __launch_bounds__(TPB) void finalize_ws_kernel(
    const float* __restrict__ ws,
    const float* __restrict__ coef,
    float* __restrict__ out)
{
    __shared__ float wsum[TPB / 64];
    const int b = blockIdx.x;
    const int t = threadIdx.x;

    float s = 0.f;
#pragma unroll
    for (int m = 0; m < NPOS / TPB; ++m) s += ws[(size_t)b * NPOS + t + m * TPB];
#pragma unroll
    for (int o = 32; o > 0; o >>= 1) s += __shfl_xor(s, o, 64);
    if ((t & 63) == 0) wsum[t >> 6] = s;
    __syncthreads();
    if (t == 0) {
        const float z = coef[0] + coef[1] + wsum[0] + wsum[1] + wsum[2] + wsum[3];
        out[b] = 1.0f / (1.0f + expf(-z));
    }
}

__global__ void init_out_kernel(float* __restrict__ out)
{
    if (threadIdx.x < BATCH) out[threadIdx.x] = 0.f;
}

__global__ void finalize_atomic_kernel(const float* __restrict__ coef,
                                       float* __restrict__ out)
{
    const int b = threadIdx.x;
    if (b < BATCH) {
        const float z = coef[0] + coef[1] + out[b];
        out[b] = 1.0f / (1.0f + expf(-z));
    }
}

extern "C" void kernel_launch(void* const* d_in, const int* in_sizes, int n_in,
                              void* d_out, int out_size, void* d_ws, size_t ws_size,
                              hipStream_t stream) {
    const float* x    = (const float*)d_in[0];   // (32, 2048, 2048) f32
    const float* Ms   = (const float*)d_in[1];   // (2, 2, 2048, 2048) f32
    const float* coef = (const float*)d_in[2];   // (2, 2) f32
    float* out = (float*)d_out;                  // (32,) f32
    float* ws  = (float*)d_ws;

    if (ws_size >= WS_NEED) {
        // Path A: partials in (checked) workspace, no atomics.
        trace_kernel<1><<<GRID_MAIN, TPB, 0, stream>>>(x, Ms, coef, ws, out);
        finalize_ws_kernel<<<BATCH, TPB, 0, stream>>>(ws, coef, out);
    } else {
        // Path B: zero workspace — accumulate via atomics into out.
        init_out_kernel<<<1, 64, 0, stream>>>(out);
        trace_kernel<0><<<GRID_MAIN, TPB, 0, stream>>>(x, Ms, coef, ws, out);
        finalize_atomic_kernel<<<1, 64, 0, stream>>>(coef, out);
    }
}